// Round 1
// baseline (299.603 us; speedup 1.0000x reference)
//
#include <hip/hip_runtime.h>
#include <hip/hip_bf16.h>

// Shapes (fixed): B=2, S=2048, D=768, H=12, DK=64.
// Reference quirks (faithful): heads split the flat (S*D) buffer => head slab
// pointer = base + bh*S*DK; PV uses PRE-softmax score; attn (softmax) is a
// second output concatenated after out in d_out.

#define S_LEN   2048
#define D_MODEL 768
#define NHEAD   12
#define DKH     64
#define BSROWS  4096            // B*S
#define NBH     24              // B*H
#define HEADSZ  (S_LEN * DKH)   // 131072 elements per (b,h) head slab

typedef __attribute__((ext_vector_type(4))) float f32x4;
typedef __attribute__((ext_vector_type(8))) short s16x8;

static __device__ __forceinline__ short f2bf(float f) {
    union { float f; unsigned u; } x; x.f = f;
    unsigned r = x.u + 0x7fffu + ((x.u >> 16) & 1u);   // RNE
    return (short)(unsigned short)(r >> 16);
}

// ---------------------------------------------------------------------------
// GEMM: C[M,768] = A[M,768] @ W[768,768]^T + bias.  Tile 64x64, K-step 64,
// 256 threads (4 waves, each 16 rows x 64 cols), bf16 MFMA 16x16x32.
// LDS layout [khalf][row][32] (64B row stride): staging writes and fragment
// reads are bank-conflict-free (row parity lands in bank bit 4).
// ---------------------------------------------------------------------------
template<int A_BF16, int OUT_F32>
__global__ __launch_bounds__(256) void gemm_bt(const void* __restrict__ Av,
                                               const float* __restrict__ W,
                                               const float* __restrict__ bias,
                                               void* __restrict__ Cv)
{
    __shared__ short As[2][64][32];
    __shared__ short Ws[2][64][32];
    const int nt = blockIdx.x, mt = blockIdx.y;
    const int t = threadIdx.x;
    const int wave = t >> 6, lane = t & 63, lrow = lane & 15, lgrp = lane >> 4;

    f32x4 acc[4];
#pragma unroll
    for (int n = 0; n < 4; ++n) acc[n] = {0.f, 0.f, 0.f, 0.f};

    for (int kk = 0; kk < 768; kk += 64) {
#pragma unroll
        for (int j = 0; j < 2; ++j) {
            int id = t + j * 256;            // 0..511: 64 rows x 8 chunks
            int row = id >> 3, ch = id & 7;
            s16x8 av;
            if (A_BF16) {
                av = *(const s16x8*)((const short*)Av + (size_t)(mt * 64 + row) * 768 + kk + ch * 8);
            } else {
                const float* src = (const float*)Av + (size_t)(mt * 64 + row) * 768 + kk + ch * 8;
                f32x4 v0 = *(const f32x4*)src;
                f32x4 v1 = *(const f32x4*)(src + 4);
                av[0] = f2bf(v0[0]); av[1] = f2bf(v0[1]); av[2] = f2bf(v0[2]); av[3] = f2bf(v0[3]);
                av[4] = f2bf(v1[0]); av[5] = f2bf(v1[1]); av[6] = f2bf(v1[2]); av[7] = f2bf(v1[3]);
            }
            *(s16x8*)&As[ch >> 2][row][(ch & 3) * 8] = av;

            const float* wsrc = W + (size_t)(nt * 64 + row) * 768 + kk + ch * 8;
            f32x4 w0 = *(const f32x4*)wsrc;
            f32x4 w1 = *(const f32x4*)(wsrc + 4);
            s16x8 wv;
            wv[0] = f2bf(w0[0]); wv[1] = f2bf(w0[1]); wv[2] = f2bf(w0[2]); wv[3] = f2bf(w0[3]);
            wv[4] = f2bf(w1[0]); wv[5] = f2bf(w1[1]); wv[6] = f2bf(w1[2]); wv[7] = f2bf(w1[3]);
            *(s16x8*)&Ws[ch >> 2][row][(ch & 3) * 8] = wv;
        }
        __syncthreads();
#pragma unroll
        for (int c = 0; c < 2; ++c) {
            s16x8 a = *(const s16x8*)&As[c][wave * 16 + lrow][lgrp * 8];
#pragma unroll
            for (int n = 0; n < 4; ++n) {
                s16x8 b = *(const s16x8*)&Ws[c][n * 16 + lrow][lgrp * 8];
                acc[n] = __builtin_amdgcn_mfma_f32_16x16x32_bf16(a, b, acc[n], 0, 0, 0);
            }
        }
        __syncthreads();
    }
    // Epilogue. C/D layout (m89-verified): col = lane&15, row = (lane>>4)*4+r.
#pragma unroll
    for (int n = 0; n < 4; ++n) {
        int col = nt * 64 + n * 16 + lrow;
        float bvv = bias[col];
#pragma unroll
        for (int r = 0; r < 4; ++r) {
            int row = mt * 64 + wave * 16 + lgrp * 4 + r;
            float v = acc[n][r] + bvv;
            if (OUT_F32) ((float*)Cv)[(size_t)row * 768 + col] = v;
            else         ((short*)Cv)[(size_t)row * 768 + col] = f2bf(v);
        }
    }
}

// ---------------------------------------------------------------------------
// Fused attention per (bh, 64-row q-block).  256 threads = 4 waves, each wave
// owns 16 q-rows.  Pass A: QK^T (bf16 MFMA, fp32 acc) -> running Z=sum(exp(s))
// (no-max softmax: |s|<~6, safe) and PV accumulation with RAW score (the
// reference bug).  Pass B: recompute QK^T (bitwise-identical) and write
// attn = exp(s)*invZ directly -> attn region written exactly once.
// ---------------------------------------------------------------------------
__global__ __launch_bounds__(256) void attn_fused(const short* __restrict__ Qb,
                                                  const short* __restrict__ Kb,
                                                  const short* __restrict__ Vb,
                                                  short* __restrict__ Ob,
                                                  float* __restrict__ attn)
{
    __shared__ short Qs[2][64][32];
    __shared__ short Ks[2][64][32];
    __shared__ short VTs[2][64][32];     // V^T: [khalf][dk][k&31 ^ ((dk>>3)&3)<<3]
    __shared__ short Ss[4][2][16][32];   // per-wave raw-score strip (bf16)

    const int qb = blockIdx.x, bh = blockIdx.y;
    const int t = threadIdx.x;
    const int wave = t >> 6, lane = t & 63, lrow = lane & 15, lgrp = lane >> 4;
    const int b = bh / NHEAD, h = bh % NHEAD;
    const short* Qh = Qb + (size_t)bh * HEADSZ;
    const short* Kh = Kb + (size_t)bh * HEADSZ;
    const short* Vh = Vb + (size_t)bh * HEADSZ;
    const int q0 = qb * 64;

    // Stage Q block [64 x 64] once.
#pragma unroll
    for (int j = 0; j < 2; ++j) {
        int id = t + j * 256;
        int row = id >> 3, ch = id & 7;
        s16x8 v = *(const s16x8*)(Qh + (size_t)(q0 + row) * DKH + ch * 8);
        *(s16x8*)&Qs[ch >> 2][row][(ch & 3) * 8] = v;
    }
    __syncthreads();
    s16x8 aq[2];
#pragma unroll
    for (int c = 0; c < 2; ++c)
        aq[c] = *(const s16x8*)&Qs[c][wave * 16 + lrow][lgrp * 8];

    f32x4 pv[4];
#pragma unroll
    for (int n = 0; n < 4; ++n) pv[n] = {0.f, 0.f, 0.f, 0.f};
    float zpart[4] = {0.f, 0.f, 0.f, 0.f};

    // ---- Pass A ----
    for (int kt = 0; kt < 32; ++kt) {
        __syncthreads();   // previous iteration's readers are done
#pragma unroll
        for (int j = 0; j < 2; ++j) {
            int id = t + j * 256;
            int row = id >> 3, ch = id & 7;
            s16x8 kv = *(const s16x8*)(Kh + (size_t)(kt * 64 + row) * DKH + ch * 8);
            *(s16x8*)&Ks[ch >> 2][row][(ch & 3) * 8] = kv;
            s16x8 vv = *(const s16x8*)(Vh + (size_t)(kt * 64 + row) * DKH + ch * 8);
#pragma unroll
            for (int e = 0; e < 8; ++e)   // transpose-scatter, ~2-way conflicts
                VTs[row >> 5][ch * 8 + e][(row & 31) ^ ((ch & 3) << 3)] = vv[e];
        }
        __syncthreads();

        float sc[4][4];
#pragma unroll
        for (int n = 0; n < 4; ++n) {
            f32x4 s = {0.f, 0.f, 0.f, 0.f};
#pragma unroll
            for (int c = 0; c < 2; ++c) {
                s16x8 bk = *(const s16x8*)&Ks[c][n * 16 + lrow][lgrp * 8];
                s = __builtin_amdgcn_mfma_f32_16x16x32_bf16(aq[c], bk, s, 0, 0, 0);
            }
#pragma unroll
            for (int r = 0; r < 4; ++r) {
                float v = s[r] * 0.125f;           // 1/sqrt(64)
                sc[n][r] = v;
                zpart[r] += __expf(v);
            }
        }
        // raw score -> wave-private LDS strip (bf16), then PV MFMA
#pragma unroll
        for (int n = 0; n < 4; ++n) {
            int kcol = n * 16 + lrow;
#pragma unroll
            for (int r = 0; r < 4; ++r)
                Ss[wave][kcol >> 5][lgrp * 4 + r][kcol & 31] = f2bf(sc[n][r]);
        }
#pragma unroll
        for (int c = 0; c < 2; ++c) {
            s16x8 as = *(const s16x8*)&Ss[wave][c][lrow][lgrp * 8];
#pragma unroll
            for (int n = 0; n < 4; ++n) {
                int vrow = n * 16 + lrow;
                s16x8 bv = *(const s16x8*)&VTs[c][vrow][(lgrp * 8) ^ ((((vrow >> 3) & 3)) << 3)];
                pv[n] = __builtin_amdgcn_mfma_f32_16x16x32_bf16(as, bv, pv[n], 0, 0, 0);
            }
        }
    }

    // Z reduce across the 16 lanes sharing lgrp (cols of a row), all lanes keep it.
    float invz[4];
#pragma unroll
    for (int r = 0; r < 4; ++r) {
        float z = zpart[r];
        z += __shfl_xor(z, 1, 16);
        z += __shfl_xor(z, 2, 16);
        z += __shfl_xor(z, 4, 16);
        z += __shfl_xor(z, 8, 16);
        invz[r] = 1.0f / z;
    }

    // ---- Pass B: recompute score, write normalized softmax ----
    float* attnw = attn + ((size_t)bh * S_LEN + (q0 + wave * 16)) * S_LEN;
    for (int kt = 0; kt < 32; ++kt) {
        __syncthreads();
#pragma unroll
        for (int j = 0; j < 2; ++j) {
            int id = t + j * 256;
            int row = id >> 3, ch = id & 7;
            s16x8 kv = *(const s16x8*)(Kh + (size_t)(kt * 64 + row) * DKH + ch * 8);
            *(s16x8*)&Ks[ch >> 2][row][(ch & 3) * 8] = kv;
        }
        __syncthreads();
#pragma unroll
        for (int n = 0; n < 4; ++n) {
            f32x4 s = {0.f, 0.f, 0.f, 0.f};
#pragma unroll
            for (int c = 0; c < 2; ++c) {
                s16x8 bk = *(const s16x8*)&Ks[c][n * 16 + lrow][lgrp * 8];
                s = __builtin_amdgcn_mfma_f32_16x16x32_bf16(aq[c], bk, s, 0, 0, 0);
            }
#pragma unroll
            for (int r = 0; r < 4; ++r) {
                float a = __expf(s[r] * 0.125f) * invz[r];
                attnw[(size_t)(lgrp * 4 + r) * S_LEN + kt * 64 + n * 16 + lrow] = a;
            }
        }
    }

    // PV epilogue: out[b, s, h*64+dk] (the transpose(0,2,1,3) concat), as bf16
    // for the final GEMM input.
#pragma unroll
    for (int n = 0; n < 4; ++n) {
#pragma unroll
        for (int r = 0; r < 4; ++r) {
            int srow = q0 + wave * 16 + lgrp * 4 + r;
            Ob[((size_t)b * S_LEN + srow) * D_MODEL + h * DKH + n * 16 + lrow] = f2bf(pv[n][r]);
        }
    }
}

// ---------------------------------------------------------------------------
extern "C" void kernel_launch(void* const* d_in, const int* in_sizes, int n_in,
                              void* d_out, int out_size, void* d_ws, size_t ws_size,
                              hipStream_t stream)
{
    const float* q  = (const float*)d_in[0];
    const float* k  = (const float*)d_in[1];
    const float* v  = (const float*)d_in[2];
    const float* Wq = (const float*)d_in[3];
    const float* bq = (const float*)d_in[4];
    const float* Wk = (const float*)d_in[5];
    const float* bk = (const float*)d_in[6];
    const float* Wv = (const float*)d_in[7];
    const float* bv = (const float*)d_in[8];
    const float* Wc = (const float*)d_in[9];
    const float* bc = (const float*)d_in[10];

    float* out  = (float*)d_out;                         // [B,S,D] = 3,145,728 f32
    float* attn = out + (size_t)BSROWS * D_MODEL;        // [B,H,S,S] = 100,663,296 f32

    // ws: Q,K,V,O as bf16 [4096,768] => 4 * 6 MiB = 24 MiB
    short* Qw = (short*)d_ws;
    short* Kw = Qw + (size_t)BSROWS * D_MODEL;
    short* Vw = Kw + (size_t)BSROWS * D_MODEL;
    short* Ow = Vw + (size_t)BSROWS * D_MODEL;

    dim3 blk(256);
    dim3 g1(12, 64);    // N-tiles x M-tiles
    gemm_bt<0, 0><<<g1, blk, 0, stream>>>(q, Wq, bq, Qw);
    gemm_bt<0, 0><<<g1, blk, 0, stream>>>(k, Wk, bk, Kw);
    gemm_bt<0, 0><<<g1, blk, 0, stream>>>(v, Wv, bv, Vw);

    dim3 g2(32, 24);    // q-blocks x (b*h)
    attn_fused<<<g2, blk, 0, stream>>>(Qw, Kw, Vw, Ow, attn);

    gemm_bt<1, 1><<<g1, blk, 0, stream>>>(Ow, Wc, bc, out);
}

// Round 2
// 289.704 us; speedup vs baseline: 1.0342x; 1.0342x over previous
//
#include <hip/hip_runtime.h>
#include <hip/hip_bf16.h>

// Shapes (fixed): B=2, S=2048, D=768, H=12, DK=64.
// Reference quirks (faithful): heads split the flat (S*D) buffer => head slab
// pointer = base + bh*S*DK; PV uses PRE-softmax score; attn (softmax) is a
// second output concatenated after out in d_out.

#define S_LEN   2048
#define D_MODEL 768
#define NHEAD   12
#define DKH     64
#define BSROWS  4096            // B*S
#define HEADSZ  (S_LEN * DKH)   // 131072 elements per (b,h) head slab

typedef __attribute__((ext_vector_type(4))) float f32x4;
typedef __attribute__((ext_vector_type(8))) short s16x8;

static __device__ __forceinline__ short f2bf(float f) {
    union { float f; unsigned u; } x; x.f = f;
    unsigned r = x.u + 0x7fffu + ((x.u >> 16) & 1u);   // RNE
    return (short)(unsigned short)(r >> 16);
}

// async global->LDS, 16B per lane; dest = wave-uniform base + lane*16
static __device__ __forceinline__ void gload16(const void* g, void* l) {
    __builtin_amdgcn_global_load_lds((const __attribute__((address_space(1))) void*)g,
                                     (__attribute__((address_space(3))) void*)l, 16, 0, 0);
}

// Swizzled fragment read from a [64][64] bf16 tile (128B rows, source-side
// chunk XOR (ch^(row&7)) at staging time). c16 = 16B-chunk index in row.
static __device__ __forceinline__ s16x8 ldfrag(const short* tile, int row, int c16) {
    int byte = row * 128 + ((c16 * 16) ^ ((row & 7) << 4));
    return *(const s16x8*)((const char*)tile + byte);
}

// ---------------------------------------------------------------------------
// GEMM: C[M,768] = A[M,768] @ W[768,768]^T + bias.  Tile 64x64, 4 waves.
// (round-1 structure, known-good)
// ---------------------------------------------------------------------------
template<int A_BF16, int OUT_F32>
static __device__ __forceinline__ void gemm_body(const void* Av, const float* W,
                                                 const float* bias, void* Cv,
                                                 int nt, int mt, int t)
{
    __shared__ short As[2][64][32];
    __shared__ short Ws[2][64][32];
    const int wave = t >> 6, lane = t & 63, lrow = lane & 15, lgrp = lane >> 4;

    f32x4 acc[4];
#pragma unroll
    for (int n = 0; n < 4; ++n) acc[n] = {0.f, 0.f, 0.f, 0.f};

    for (int kk = 0; kk < 768; kk += 64) {
        __syncthreads();
#pragma unroll
        for (int j = 0; j < 2; ++j) {
            int id = t + j * 256;
            int row = id >> 3, ch = id & 7;
            s16x8 av;
            if (A_BF16) {
                av = *(const s16x8*)((const short*)Av + (size_t)(mt * 64 + row) * 768 + kk + ch * 8);
            } else {
                const float* src = (const float*)Av + (size_t)(mt * 64 + row) * 768 + kk + ch * 8;
                f32x4 v0 = *(const f32x4*)src;
                f32x4 v1 = *(const f32x4*)(src + 4);
                av[0] = f2bf(v0[0]); av[1] = f2bf(v0[1]); av[2] = f2bf(v0[2]); av[3] = f2bf(v0[3]);
                av[4] = f2bf(v1[0]); av[5] = f2bf(v1[1]); av[6] = f2bf(v1[2]); av[7] = f2bf(v1[3]);
            }
            *(s16x8*)&As[ch >> 2][row][(ch & 3) * 8] = av;

            const float* wsrc = W + (size_t)(nt * 64 + row) * 768 + kk + ch * 8;
            f32x4 w0 = *(const f32x4*)wsrc;
            f32x4 w1 = *(const f32x4*)(wsrc + 4);
            s16x8 wv;
            wv[0] = f2bf(w0[0]); wv[1] = f2bf(w0[1]); wv[2] = f2bf(w0[2]); wv[3] = f2bf(w0[3]);
            wv[4] = f2bf(w1[0]); wv[5] = f2bf(w1[1]); wv[6] = f2bf(w1[2]); wv[7] = f2bf(w1[3]);
            *(s16x8*)&Ws[ch >> 2][row][(ch & 3) * 8] = wv;
        }
        __syncthreads();
#pragma unroll
        for (int c = 0; c < 2; ++c) {
            s16x8 a = *(const s16x8*)&As[c][wave * 16 + lrow][lgrp * 8];
#pragma unroll
            for (int n = 0; n < 4; ++n) {
                s16x8 b = *(const s16x8*)&Ws[c][n * 16 + lrow][lgrp * 8];
                acc[n] = __builtin_amdgcn_mfma_f32_16x16x32_bf16(a, b, acc[n], 0, 0, 0);
            }
        }
    }
#pragma unroll
    for (int n = 0; n < 4; ++n) {
        int col = nt * 64 + n * 16 + lrow;
        float bvv = bias[col];
#pragma unroll
        for (int r = 0; r < 4; ++r) {
            int row = mt * 64 + wave * 16 + lgrp * 4 + r;
            float v = acc[n][r] + bvv;
            if (OUT_F32) ((float*)Cv)[(size_t)row * 768 + col] = v;
            else         ((short*)Cv)[(size_t)row * 768 + col] = f2bf(v);
        }
    }
}

__global__ __launch_bounds__(256) void gemm_qkv(const float* __restrict__ q,
                                                const float* __restrict__ k,
                                                const float* __restrict__ v,
                                                const float* __restrict__ Wq,
                                                const float* __restrict__ Wk,
                                                const float* __restrict__ Wv,
                                                const float* __restrict__ bq,
                                                const float* __restrict__ bk,
                                                const float* __restrict__ bv,
                                                short* __restrict__ Qw,
                                                short* __restrict__ Kw,
                                                short* __restrict__ Vw)
{
    const float *A, *W, *bias; short* C;
    if (blockIdx.z == 0)      { A = q; W = Wq; bias = bq; C = Qw; }
    else if (blockIdx.z == 1) { A = k; W = Wk; bias = bk; C = Kw; }
    else                      { A = v; W = Wv; bias = bv; C = Vw; }
    gemm_body<0, 0>(A, W, bias, C, blockIdx.x, blockIdx.y, threadIdx.x);
}

__global__ __launch_bounds__(256) void gemm_out(const short* __restrict__ Ow,
                                                const float* __restrict__ Wc,
                                                const float* __restrict__ bc,
                                                float* __restrict__ out)
{
    gemm_body<1, 1>(Ow, Wc, bc, out, blockIdx.x, blockIdx.y, threadIdx.x);
}

// ---------------------------------------------------------------------------
// V^T per head: Vt[bh][dk][s] from Vw head slab [bh][s][dk].  L1-backed
// strided gathers, coalesced b128 writes.
// ---------------------------------------------------------------------------
__global__ __launch_bounds__(256) void vtrans(const short* __restrict__ Vw,
                                              short* __restrict__ Vt)
{
    const int sblk = blockIdx.x, bh = blockIdx.y;
    const short* src = Vw + (size_t)bh * HEADSZ;
    short* dst = Vt + (size_t)bh * HEADSZ;
    const int t = threadIdx.x;
#pragma unroll
    for (int j = 0; j < 2; ++j) {
        int cid = t + j * 256, dk = cid >> 3, ch = cid & 7;
        int s0 = sblk * 64 + ch * 8;
        s16x8 vv;
#pragma unroll
        for (int e = 0; e < 8; ++e) vv[e] = src[(size_t)(s0 + e) * DKH + dk];
        *(s16x8*)(dst + (size_t)dk * S_LEN + s0) = vv;
    }
}

// ---------------------------------------------------------------------------
// Fused attention.  128 threads = 2 waves, each wave owns 32 q-rows.
// Pass A: QK^T -> Z partials + PV (raw score, the reference bug).
// Pass B: recompute QK^T, write attn = exp(s)*invZ (single write of 402MB).
// K/V double-buffered, staged via global_load_lds w/ source XOR swizzle;
// one barrier per kt (loads for kt+1 fly under compute of kt).
// ---------------------------------------------------------------------------
__global__ __launch_bounds__(128) void attn_fused(const short* __restrict__ Qb,
                                                  const short* __restrict__ Kb,
                                                  const short* __restrict__ Vtb,
                                                  short* __restrict__ Ob,
                                                  float* __restrict__ attn)
{
    __shared__ short Qs[4096];          // [64 q][64 k]  swizzled
    __shared__ short Ks[2][4096];       // [64 kpos][64 dk]
    __shared__ short Vs[2][4096];       // [64 dk][64 kpos]  (from Vt)
    __shared__ short Ss[2][2048];       // per-wave [32 q][64 kpos] swizzled

    const int bid = blockIdx.x;
    const int swz = (bid & 7) * 96 + (bid >> 3);     // XCD-contiguous heads
    const int qb = swz & 31, bh = swz >> 5;
    const int t = threadIdx.x, w = t >> 6, lane = t & 63;
    const int lrow = lane & 15, lgrp = lane >> 4;
    const int b = bh / NHEAD, h = bh % NHEAD;
    const short* Qh = Qb + (size_t)bh * HEADSZ;
    const short* Kh = Kb + (size_t)bh * HEADSZ;
    const short* Vth = Vtb + (size_t)bh * HEADSZ;    // [64 dk][2048 s]
    const int q0 = qb * 64;

#define STAGE_KV(buf, kt) do {                                                  \
    _Pragma("unroll")                                                           \
    for (int j = 0; j < 4; ++j) {                                               \
        int cid = t + j * 128, row = cid >> 3, ch = cid & 7;                    \
        int cs = (ch ^ (row & 7)) * 8;                                          \
        gload16(Kh + (size_t)((kt) * 64 + row) * DKH + cs,                      \
                (short*)Ks[buf] + w * 512 + j * 1024);                          \
        gload16(Vth + (size_t)row * S_LEN + (kt) * 64 + cs,                     \
                (short*)Vs[buf] + w * 512 + j * 1024);                          \
    } } while (0)

#define STAGE_K(buf, kt) do {                                                   \
    _Pragma("unroll")                                                           \
    for (int j = 0; j < 4; ++j) {                                               \
        int cid = t + j * 128, row = cid >> 3, ch = cid & 7;                    \
        int cs = (ch ^ (row & 7)) * 8;                                          \
        gload16(Kh + (size_t)((kt) * 64 + row) * DKH + cs,                      \
                (short*)Ks[buf] + w * 512 + j * 1024);                          \
    } } while (0)

    // Stage Q (once) + first K/V tile.
#pragma unroll
    for (int j = 0; j < 4; ++j) {
        int cid = t + j * 128, row = cid >> 3, ch = cid & 7;
        int cs = (ch ^ (row & 7)) * 8;
        gload16(Qh + (size_t)(q0 + row) * DKH + cs, (short*)Qs + w * 512 + j * 1024);
    }
    STAGE_KV(0, 0);
    __syncthreads();

    s16x8 aq[2][2];
#pragma unroll
    for (int m = 0; m < 2; ++m)
#pragma unroll
        for (int c = 0; c < 2; ++c)
            aq[m][c] = ldfrag(Qs, w * 32 + m * 16 + lrow, c * 4 + lgrp);

    f32x4 pv[2][4];
#pragma unroll
    for (int m = 0; m < 2; ++m)
#pragma unroll
        for (int n = 0; n < 4; ++n) pv[m][n] = {0.f, 0.f, 0.f, 0.f};
    float zp[2][4] = {{0.f,0.f,0.f,0.f},{0.f,0.f,0.f,0.f}};

    short* SW = Ss[w];
    int cur = 0;

    // ---- Pass A ----
    for (int kt = 0; kt < 32; ++kt) {
        if (kt) __syncthreads();               // buf[cur] ready; buf[cur^1] free
        if (kt < 31) STAGE_KV(cur ^ 1, kt + 1);

#pragma unroll
        for (int n = 0; n < 4; ++n) {
            f32x4 s0 = {0.f,0.f,0.f,0.f}, s1 = {0.f,0.f,0.f,0.f};
            __builtin_amdgcn_s_setprio(1);
#pragma unroll
            for (int c = 0; c < 2; ++c) {
                s16x8 bk = ldfrag(Ks[cur], n * 16 + lrow, c * 4 + lgrp);
                s0 = __builtin_amdgcn_mfma_f32_16x16x32_bf16(aq[0][c], bk, s0, 0, 0, 0);
                s1 = __builtin_amdgcn_mfma_f32_16x16x32_bf16(aq[1][c], bk, s1, 0, 0, 0);
            }
            __builtin_amdgcn_s_setprio(0);
            int kcol2 = (n * 16 + lrow) * 2;
#pragma unroll
            for (int r = 0; r < 4; ++r) {
                float v0 = s0[r] * 0.125f, v1 = s1[r] * 0.125f;
                zp[0][r] += __expf(v0);
                zp[1][r] += __expf(v1);
                int qa = lgrp * 4 + r, qb2 = 16 + qa;
                *(short*)((char*)SW + qa * 128 + (kcol2 ^ ((qa & 7) << 4))) = f2bf(v0);
                *(short*)((char*)SW + qb2 * 128 + (kcol2 ^ ((qb2 & 7) << 4))) = f2bf(v1);
            }
        }
        s16x8 as[2][2];
#pragma unroll
        for (int m = 0; m < 2; ++m)
#pragma unroll
            for (int c = 0; c < 2; ++c)
                as[m][c] = ldfrag(SW, m * 16 + lrow, c * 4 + lgrp);
        __builtin_amdgcn_s_setprio(1);
#pragma unroll
        for (int n = 0; n < 4; ++n) {
#pragma unroll
            for (int c = 0; c < 2; ++c) {
                s16x8 bv = ldfrag(Vs[cur], n * 16 + lrow, c * 4 + lgrp);
                pv[0][n] = __builtin_amdgcn_mfma_f32_16x16x32_bf16(as[0][c], bv, pv[0][n], 0, 0, 0);
                pv[1][n] = __builtin_amdgcn_mfma_f32_16x16x32_bf16(as[1][c], bv, pv[1][n], 0, 0, 0);
            }
        }
        __builtin_amdgcn_s_setprio(0);
        cur ^= 1;
    }

    // Z reduce across the 16 lanes of each row group.
    float invz[2][4];
#pragma unroll
    for (int m = 0; m < 2; ++m)
#pragma unroll
        for (int r = 0; r < 4; ++r) {
            float z = zp[m][r];
            z += __shfl_xor(z, 1, 16);
            z += __shfl_xor(z, 2, 16);
            z += __shfl_xor(z, 4, 16);
            z += __shfl_xor(z, 8, 16);
            invz[m][r] = 1.0f / z;
        }

    // PV epilogue -> Ob (bf16, concat layout) — stores fly under pass B.
#pragma unroll
    for (int m = 0; m < 2; ++m)
#pragma unroll
        for (int n = 0; n < 4; ++n)
#pragma unroll
            for (int r = 0; r < 4; ++r) {
                int srow = q0 + w * 32 + m * 16 + lgrp * 4 + r;
                Ob[((size_t)b * S_LEN + srow) * D_MODEL + h * DKH + n * 16 + lrow]
                    = f2bf(pv[m][n][r]);
            }

    // ---- Pass B: recompute score, write attn ----
    __syncthreads();
    STAGE_K(0, 0);
    cur = 0;
    float* aw = attn + (size_t)bh * S_LEN * S_LEN;
    for (int kt = 0; kt < 32; ++kt) {
        __syncthreads();
        if (kt < 31) STAGE_K(cur ^ 1, kt + 1);
#pragma unroll
        for (int n = 0; n < 4; ++n) {
            f32x4 s0 = {0.f,0.f,0.f,0.f}, s1 = {0.f,0.f,0.f,0.f};
            __builtin_amdgcn_s_setprio(1);
#pragma unroll
            for (int c = 0; c < 2; ++c) {
                s16x8 bk = ldfrag(Ks[cur], n * 16 + lrow, c * 4 + lgrp);
                s0 = __builtin_amdgcn_mfma_f32_16x16x32_bf16(aq[0][c], bk, s0, 0, 0, 0);
                s1 = __builtin_amdgcn_mfma_f32_16x16x32_bf16(aq[1][c], bk, s1, 0, 0, 0);
            }
            __builtin_amdgcn_s_setprio(0);
            int kcol = kt * 64 + n * 16 + lrow;
#pragma unroll
            for (int r = 0; r < 4; ++r) {
                float a0 = __expf(s0[r] * 0.125f) * invz[0][r];
                float a1 = __expf(s1[r] * 0.125f) * invz[1][r];
                size_t row0 = (size_t)(q0 + w * 32 + lgrp * 4 + r);
                aw[(row0) * S_LEN + kcol] = a0;
                aw[(row0 + 16) * S_LEN + kcol] = a1;
            }
        }
        cur ^= 1;
    }
#undef STAGE_KV
#undef STAGE_K
}

// ---------------------------------------------------------------------------
extern "C" void kernel_launch(void* const* d_in, const int* in_sizes, int n_in,
                              void* d_out, int out_size, void* d_ws, size_t ws_size,
                              hipStream_t stream)
{
    const float* q  = (const float*)d_in[0];
    const float* k  = (const float*)d_in[1];
    const float* v  = (const float*)d_in[2];
    const float* Wq = (const float*)d_in[3];
    const float* bq = (const float*)d_in[4];
    const float* Wk = (const float*)d_in[5];
    const float* bk = (const float*)d_in[6];
    const float* Wv = (const float*)d_in[7];
    const float* bv = (const float*)d_in[8];
    const float* Wc = (const float*)d_in[9];
    const float* bc = (const float*)d_in[10];

    float* out  = (float*)d_out;
    float* attn = out + (size_t)BSROWS * D_MODEL;

    short* Qw = (short*)d_ws;
    short* Kw = Qw + (size_t)BSROWS * D_MODEL;
    short* Vw = Kw + (size_t)BSROWS * D_MODEL;
    short* Ow = Vw + (size_t)BSROWS * D_MODEL;
    short* Vt = Ow + (size_t)BSROWS * D_MODEL;   // [24][64][2048] bf16

    dim3 blk(256);
    dim3 g1(12, 64, 3);
    gemm_qkv<<<g1, blk, 0, stream>>>(q, k, v, Wq, Wk, Wv, bq, bk, bv, Qw, Kw, Vw);

    dim3 gt(32, 24);
    vtrans<<<gt, blk, 0, stream>>>(Vw, Vt);

    attn_fused<<<dim3(768), dim3(128), 0, stream>>>(Qw, Kw, Vt, Ow, attn);

    gemm_out<<<dim3(12, 64), blk, 0, stream>>>(Ow, Wc, bc, out);
}

// Round 3
// 262.590 us; speedup vs baseline: 1.1410x; 1.1033x over previous
//
#include <hip/hip_runtime.h>
#include <hip/hip_bf16.h>

// Shapes (fixed): B=2, S=2048, D=768, H=12, DK=64.
// Reference quirks (faithful): heads split the flat (S*D) buffer => head slab
// pointer = base + bh*S*DK; PV uses PRE-softmax score; attn (softmax) is a
// second output concatenated after out in d_out.

#define S_LEN   2048
#define D_MODEL 768
#define NHEAD   12
#define DKH     64
#define BSROWS  4096            // B*S
#define HEADSZ  (S_LEN * DKH)   // 131072 elements per (b,h) head slab
#define WELEMS  (D_MODEL * D_MODEL)   // 589824

typedef __attribute__((ext_vector_type(4))) float f32x4;
typedef __attribute__((ext_vector_type(8))) short s16x8;

static __device__ __forceinline__ short f2bf(float f) {
    union { float f; unsigned u; } x; x.f = f;
    unsigned r = x.u + 0x7fffu + ((x.u >> 16) & 1u);   // RNE
    return (short)(unsigned short)(r >> 16);
}

static __device__ __forceinline__ s16x8 cvt8(f32x4 a, f32x4 b) {
    s16x8 o;
    o[0] = f2bf(a[0]); o[1] = f2bf(a[1]); o[2] = f2bf(a[2]); o[3] = f2bf(a[3]);
    o[4] = f2bf(b[0]); o[5] = f2bf(b[1]); o[6] = f2bf(b[2]); o[7] = f2bf(b[3]);
    return o;
}

// async global->LDS, 16B/lane; lds dest must be wave-uniform (HW adds lane*16)
static __device__ __forceinline__ void gload16(const void* g, void* l) {
    __builtin_amdgcn_global_load_lds((const __attribute__((address_space(1))) void*)g,
                                     (__attribute__((address_space(3))) void*)l, 16, 0, 0);
}

// Swizzled fragment read from a [rows][64] bf16 tile (128B rows; chunks were
// stored at (c ^ (row&7))). c16 = 16B-chunk index 0..7.
static __device__ __forceinline__ s16x8 ldfrag(const short* tile, int row, int c16) {
    int byte = row * 128 + ((c16 * 16) ^ ((row & 7) << 4));
    return *(const s16x8*)((const char*)tile + byte);
}

// ---------------------------------------------------------------------------
// W f32 -> bf16 prepass (4 matrices of 768x768)
// ---------------------------------------------------------------------------
__global__ __launch_bounds__(256) void prep_w(const float* __restrict__ W0,
                                              const float* __restrict__ W1,
                                              const float* __restrict__ W2,
                                              const float* __restrict__ W3,
                                              short* __restrict__ dst)
{
    const float* src = (blockIdx.y == 0) ? W0 : (blockIdx.y == 1) ? W1
                     : (blockIdx.y == 2) ? W2 : W3;
    short* d = dst + (size_t)blockIdx.y * WELEMS;
    int i = (blockIdx.x * 256 + threadIdx.x) * 8;
    f32x4 a = *(const f32x4*)(src + i);
    f32x4 b = *(const f32x4*)(src + i + 4);
    *(s16x8*)(d + i) = cvt8(a, b);
}

// ---------------------------------------------------------------------------
// GEMM 128x128 tile, BK=64, 256 threads = 4 waves (2x2), each wave 64x64.
// B (weights, bf16) staged via global_load_lds w/ source XOR swizzle.
// A: f32 reg-staged+converted, or bf16 gload (A_F32=0).
// ---------------------------------------------------------------------------
template<int A_F32, int OUT_F32>
static __device__ __forceinline__ void gemm_body128(const void* __restrict__ Av,
                                                    const short* __restrict__ Wb,
                                                    const float* __restrict__ bias,
                                                    void* __restrict__ Cv,
                                                    int mt, int nt)
{
    __shared__ short As[8192];   // [128][64] swizzled
    __shared__ short Bs[8192];
    const int t = threadIdx.x, w = t >> 6, lane = t & 63;
    const int lrow = lane & 15, lgrp = lane >> 4;
    const int wr = w >> 1, wc = w & 1;

    f32x4 acc[4][4];
#pragma unroll
    for (int m = 0; m < 4; ++m)
#pragma unroll
        for (int n = 0; n < 4; ++n) acc[m][n] = {0.f, 0.f, 0.f, 0.f};

    for (int kk = 0; kk < 768; kk += 64) {
        __syncthreads();
#pragma unroll
        for (int j = 0; j < 4; ++j) {              // B tile: 16KB via gload
            int cid = t + j * 256, row = cid >> 3, ch = cid & 7;
            gload16(Wb + (size_t)(nt * 128 + row) * 768 + kk + ((ch ^ (row & 7)) * 8),
                    (char*)Bs + j * 4096 + w * 1024);
        }
        if (A_F32) {
#pragma unroll
            for (int j = 0; j < 2; ++j) {          // A tile: f32 -> bf16 regs -> LDS
                int cid = t + j * 256, row = cid >> 2, q4 = cid & 3;
                const float* src = (const float*)Av + (size_t)(mt * 128 + row) * 768 + kk + q4 * 16;
                f32x4 v0 = *(const f32x4*)(src);
                f32x4 v1 = *(const f32x4*)(src + 4);
                f32x4 v2 = *(const f32x4*)(src + 8);
                f32x4 v3 = *(const f32x4*)(src + 12);
                int c0 = q4 * 2;
                *(s16x8*)((char*)As + row * 128 + (((c0    ) ^ (row & 7)) * 16)) = cvt8(v0, v1);
                *(s16x8*)((char*)As + row * 128 + (((c0 + 1) ^ (row & 7)) * 16)) = cvt8(v2, v3);
            }
        } else {
#pragma unroll
            for (int j = 0; j < 4; ++j) {
                int cid = t + j * 256, row = cid >> 3, ch = cid & 7;
                gload16((const short*)Av + (size_t)(mt * 128 + row) * 768 + kk + ((ch ^ (row & 7)) * 8),
                        (char*)As + j * 4096 + w * 1024);
            }
        }
        __syncthreads();
#pragma unroll
        for (int kc = 0; kc < 2; ++kc) {
            s16x8 af[4], bfr[4];
#pragma unroll
            for (int m = 0; m < 4; ++m) af[m] = ldfrag(As, wr * 64 + m * 16 + lrow, kc * 4 + lgrp);
#pragma unroll
            for (int n = 0; n < 4; ++n) bfr[n] = ldfrag(Bs, wc * 64 + n * 16 + lrow, kc * 4 + lgrp);
            __builtin_amdgcn_s_setprio(1);
#pragma unroll
            for (int m = 0; m < 4; ++m)
#pragma unroll
                for (int n = 0; n < 4; ++n)
                    acc[m][n] = __builtin_amdgcn_mfma_f32_16x16x32_bf16(af[m], bfr[n], acc[m][n], 0, 0, 0);
            __builtin_amdgcn_s_setprio(0);
        }
    }
#pragma unroll
    for (int n = 0; n < 4; ++n) {
        int col = nt * 128 + wc * 64 + n * 16 + lrow;
        float bvv = bias[col];
#pragma unroll
        for (int m = 0; m < 4; ++m)
#pragma unroll
            for (int r = 0; r < 4; ++r) {
                int row = mt * 128 + wr * 64 + m * 16 + lgrp * 4 + r;
                float v = acc[m][n][r] + bvv;
                if (OUT_F32) ((float*)Cv)[(size_t)row * 768 + col] = v;
                else         ((short*)Cv)[(size_t)row * 768 + col] = f2bf(v);
            }
    }
}

// QKV fused: 576 blocks 1-D; panel-chunked XCD swizzle so the 6 nt-blocks of
// an A-panel run on one XCD (A-panel L2-resident, read ~once).
__global__ __launch_bounds__(256) void gemm_qkv(const float* __restrict__ q,
                                                const float* __restrict__ k,
                                                const float* __restrict__ v,
                                                const short* __restrict__ Wbf,
                                                const float* __restrict__ bq,
                                                const float* __restrict__ bk,
                                                const float* __restrict__ bv,
                                                short* __restrict__ Qw,
                                                short* __restrict__ Kw,
                                                short* __restrict__ Vw)
{
    const int bid = blockIdx.x;
    const int idx = bid >> 3;
    const int panel = (bid & 7) * 12 + idx / 6;    // 96 panels = 32 mt x 3 z
    const int nt = idx % 6;
    const int z = panel / 32, mt = panel % 32;
    const float* A; const float* bias; short* C;
    if (z == 0)      { A = q; bias = bq; C = Qw; }
    else if (z == 1) { A = k; bias = bk; C = Kw; }
    else             { A = v; bias = bv; C = Vw; }
    gemm_body128<1, 0>(A, Wbf + (size_t)z * WELEMS, bias, C, mt, nt);
}

__global__ __launch_bounds__(256) void gemm_out(const short* __restrict__ Ob,
                                                const short* __restrict__ Wcb,
                                                const float* __restrict__ bc,
                                                float* __restrict__ out)
{
    const int bid = blockIdx.x;
    const int idx = bid >> 3;
    const int panel = (bid & 7) * 4 + idx / 6;     // 32 panels
    const int nt = idx % 6;
    gemm_body128<0, 1>(Ob, Wcb, bc, out, panel, nt);
}

// ---------------------------------------------------------------------------
// V^T per head: Vt[bh][dk][s2] from Vw slab [bh][s2][dk].
// ---------------------------------------------------------------------------
__global__ __launch_bounds__(256) void vtrans(const short* __restrict__ Vw,
                                              short* __restrict__ Vt)
{
    const int sblk = blockIdx.x, bh = blockIdx.y;
    const short* src = Vw + (size_t)bh * HEADSZ;
    short* dst = Vt + (size_t)bh * HEADSZ;
    const int t = threadIdx.x;
#pragma unroll
    for (int j = 0; j < 2; ++j) {
        int cid = t + j * 256, dk = cid >> 3, ch = cid & 7;
        int s0 = sblk * 64 + ch * 8;
        s16x8 vv;
#pragma unroll
        for (int e = 0; e < 8; ++e) vv[e] = src[(size_t)(s0 + e) * DKH + dk];
        *(s16x8*)(dst + (size_t)dk * S_LEN + s0) = vv;
    }
}

// ---------------------------------------------------------------------------
// Attention pass A: QK^T -> Z partials + PV with RAW score (reference bug).
// 128 threads = 2 waves x 32 q-rows. Outputs: Ob (bf16 concat layout), invz.
// ---------------------------------------------------------------------------
__global__ __launch_bounds__(128) void attn_a(const short* __restrict__ Qb,
                                              const short* __restrict__ Kb,
                                              const short* __restrict__ Vtb,
                                              short* __restrict__ Ob,
                                              float* __restrict__ invzg)
{
    __shared__ short Qs[4096];          // [64 q][64 dk]  swizzled
    __shared__ short Ks[2][4096];       // [64 kpos][64 dk]
    __shared__ short Vs[2][4096];       // [64 dk][64 kpos] (from Vt)
    __shared__ short Ss[2][2048];       // per-wave [32 q][64 kpos] swizzled

    const int bid = blockIdx.x;
    const int swz = (bid & 7) * 96 + (bid >> 3);
    const int qb = swz & 31, bh = swz >> 5;
    const int t = threadIdx.x, w = t >> 6, lane = t & 63;
    const int lrow = lane & 15, lgrp = lane >> 4;
    const int b = bh / NHEAD, h = bh % NHEAD;
    const short* Qh = Qb + (size_t)bh * HEADSZ;
    const short* Kh = Kb + (size_t)bh * HEADSZ;
    const short* Vth = Vtb + (size_t)bh * HEADSZ;
    const int q0 = qb * 64;

#define STAGE_KV(buf, kt) do {                                                  \
    _Pragma("unroll")                                                           \
    for (int j = 0; j < 4; ++j) {                                               \
        int cid = t + j * 128, row = cid >> 3, ch = cid & 7;                    \
        int cs = (ch ^ (row & 7)) * 8;                                          \
        gload16(Kh + (size_t)((kt) * 64 + row) * DKH + cs,                      \
                (short*)Ks[buf] + w * 512 + j * 1024);                          \
        gload16(Vth + (size_t)row * S_LEN + (kt) * 64 + cs,                     \
                (short*)Vs[buf] + w * 512 + j * 1024);                          \
    } } while (0)

#pragma unroll
    for (int j = 0; j < 4; ++j) {
        int cid = t + j * 128, row = cid >> 3, ch = cid & 7;
        int cs = (ch ^ (row & 7)) * 8;
        gload16(Qh + (size_t)(q0 + row) * DKH + cs, (short*)Qs + w * 512 + j * 1024);
    }
    STAGE_KV(0, 0);
    __syncthreads();

    s16x8 aq[2][2];
#pragma unroll
    for (int m = 0; m < 2; ++m)
#pragma unroll
        for (int c = 0; c < 2; ++c)
            aq[m][c] = ldfrag(Qs, w * 32 + m * 16 + lrow, c * 4 + lgrp);

    f32x4 pv[2][4];
#pragma unroll
    for (int m = 0; m < 2; ++m)
#pragma unroll
        for (int n = 0; n < 4; ++n) pv[m][n] = {0.f, 0.f, 0.f, 0.f};
    float zp[2][4] = {{0.f,0.f,0.f,0.f},{0.f,0.f,0.f,0.f}};

    short* SW = Ss[w];
    int cur = 0;

    for (int kt = 0; kt < 32; ++kt) {
        if (kt) __syncthreads();
        if (kt < 31) STAGE_KV(cur ^ 1, kt + 1);

#pragma unroll
        for (int n = 0; n < 4; ++n) {
            f32x4 s0 = {0.f,0.f,0.f,0.f}, s1 = {0.f,0.f,0.f,0.f};
            __builtin_amdgcn_s_setprio(1);
#pragma unroll
            for (int c = 0; c < 2; ++c) {
                s16x8 bk = ldfrag(Ks[cur], n * 16 + lrow, c * 4 + lgrp);
                s0 = __builtin_amdgcn_mfma_f32_16x16x32_bf16(aq[0][c], bk, s0, 0, 0, 0);
                s1 = __builtin_amdgcn_mfma_f32_16x16x32_bf16(aq[1][c], bk, s1, 0, 0, 0);
            }
            __builtin_amdgcn_s_setprio(0);
            int kcol2 = (n * 16 + lrow) * 2;
#pragma unroll
            for (int r = 0; r < 4; ++r) {
                float v0 = s0[r] * 0.125f, v1 = s1[r] * 0.125f;
                zp[0][r] += __expf(v0);
                zp[1][r] += __expf(v1);
                int qa = lgrp * 4 + r, qb2 = 16 + qa;
                *(short*)((char*)SW + qa * 128 + (kcol2 ^ ((qa & 7) << 4))) = f2bf(v0);
                *(short*)((char*)SW + qb2 * 128 + (kcol2 ^ ((qb2 & 7) << 4))) = f2bf(v1);
            }
        }
        s16x8 as[2][2];
#pragma unroll
        for (int m = 0; m < 2; ++m)
#pragma unroll
            for (int c = 0; c < 2; ++c)
                as[m][c] = ldfrag(SW, m * 16 + lrow, c * 4 + lgrp);
        __builtin_amdgcn_s_setprio(1);
#pragma unroll
        for (int n = 0; n < 4; ++n) {
#pragma unroll
            for (int c = 0; c < 2; ++c) {
                s16x8 bv = ldfrag(Vs[cur], n * 16 + lrow, c * 4 + lgrp);
                pv[0][n] = __builtin_amdgcn_mfma_f32_16x16x32_bf16(as[0][c], bv, pv[0][n], 0, 0, 0);
                pv[1][n] = __builtin_amdgcn_mfma_f32_16x16x32_bf16(as[1][c], bv, pv[1][n], 0, 0, 0);
            }
        }
        __builtin_amdgcn_s_setprio(0);
        cur ^= 1;
    }

    // Z reduce over the 16 lanes of each row group; write invz once per q-row.
#pragma unroll
    for (int m = 0; m < 2; ++m)
#pragma unroll
        for (int r = 0; r < 4; ++r) {
            float z = zp[m][r];
            z += __shfl_xor(z, 1, 16);
            z += __shfl_xor(z, 2, 16);
            z += __shfl_xor(z, 4, 16);
            z += __shfl_xor(z, 8, 16);
            if (lrow == 0)
                invzg[(size_t)bh * S_LEN + q0 + w * 32 + m * 16 + lgrp * 4 + r] = 1.0f / z;
        }

    // PV epilogue -> Ob (bf16, concat layout out[b][s][h*64+dk]).
#pragma unroll
    for (int m = 0; m < 2; ++m)
#pragma unroll
        for (int n = 0; n < 4; ++n)
#pragma unroll
            for (int r = 0; r < 4; ++r) {
                int srow = q0 + w * 32 + m * 16 + lgrp * 4 + r;
                Ob[((size_t)b * S_LEN + srow) * D_MODEL + h * DKH + n * 16 + lrow]
                    = f2bf(pv[m][n][r]);
            }
#undef STAGE_KV
}

// ---------------------------------------------------------------------------
// Attention pass B: recompute QK^T with SWAPPED operands -> lane holds 4
// consecutive kpos for one q -> f32x4 stores of attn = exp(s)*invz.
// LDS only Q + K dbuf (24KB) -> 6 blocks/CU for store-queue depth.
// ---------------------------------------------------------------------------
__global__ __launch_bounds__(128) void attn_b(const short* __restrict__ Qb,
                                              const short* __restrict__ Kb,
                                              const float* __restrict__ invzg,
                                              float* __restrict__ attn)
{
    __shared__ short Qs[4096];
    __shared__ short Ks[2][4096];

    const int bid = blockIdx.x;
    const int swz = (bid & 7) * 96 + (bid >> 3);
    const int qb = swz & 31, bh = swz >> 5;
    const int t = threadIdx.x, w = t >> 6, lane = t & 63;
    const int lrow = lane & 15, lgrp = lane >> 4;
    const short* Qh = Qb + (size_t)bh * HEADSZ;
    const short* Kh = Kb + (size_t)bh * HEADSZ;
    const int q0 = qb * 64;

#define STAGE_K(buf, kt) do {                                                   \
    _Pragma("unroll")                                                           \
    for (int j = 0; j < 4; ++j) {                                               \
        int cid = t + j * 128, row = cid >> 3, ch = cid & 7;                    \
        int cs = (ch ^ (row & 7)) * 8;                                          \
        gload16(Kh + (size_t)((kt) * 64 + row) * DKH + cs,                      \
                (short*)Ks[buf] + w * 512 + j * 1024);                          \
    } } while (0)

#pragma unroll
    for (int j = 0; j < 4; ++j) {
        int cid = t + j * 128, row = cid >> 3, ch = cid & 7;
        int cs = (ch ^ (row & 7)) * 8;
        gload16(Qh + (size_t)(q0 + row) * DKH + cs, (short*)Qs + w * 512 + j * 1024);
    }
    STAGE_K(0, 0);
    __syncthreads();

    s16x8 aq[2][2];
#pragma unroll
    for (int m = 0; m < 2; ++m)
#pragma unroll
        for (int c = 0; c < 2; ++c)
            aq[m][c] = ldfrag(Qs, w * 32 + m * 16 + lrow, c * 4 + lgrp);

    float invzq[2];
#pragma unroll
    for (int m = 0; m < 2; ++m)
        invzq[m] = invzg[(size_t)bh * S_LEN + q0 + w * 32 + m * 16 + lrow];

    float* aw = attn + (size_t)bh * S_LEN * S_LEN;
    int cur = 0;
    for (int kt = 0; kt < 32; ++kt) {
        if (kt) __syncthreads();
        if (kt < 31) STAGE_K(cur ^ 1, kt + 1);
#pragma unroll
        for (int n = 0; n < 4; ++n) {
            f32x4 s0 = {0.f,0.f,0.f,0.f}, s1 = {0.f,0.f,0.f,0.f};
            __builtin_amdgcn_s_setprio(1);
#pragma unroll
            for (int c = 0; c < 2; ++c) {
                s16x8 bk = ldfrag(Ks[cur], n * 16 + lrow, c * 4 + lgrp);
                s0 = __builtin_amdgcn_mfma_f32_16x16x32_bf16(bk, aq[0][c], s0, 0, 0, 0);
                s1 = __builtin_amdgcn_mfma_f32_16x16x32_bf16(bk, aq[1][c], s1, 0, 0, 0);
            }
            __builtin_amdgcn_s_setprio(0);
            f32x4 a0, a1;
#pragma unroll
            for (int r = 0; r < 4; ++r) {
                a0[r] = __expf(s0[r] * 0.125f) * invzq[0];
                a1[r] = __expf(s1[r] * 0.125f) * invzq[1];
            }
            int kbase = kt * 64 + n * 16 + lgrp * 4;
            *(f32x4*)(aw + (size_t)(q0 + w * 32 + lrow) * S_LEN + kbase) = a0;
            *(f32x4*)(aw + (size_t)(q0 + w * 32 + 16 + lrow) * S_LEN + kbase) = a1;
        }
        cur ^= 1;
    }
#undef STAGE_K
}

// ---------------------------------------------------------------------------
extern "C" void kernel_launch(void* const* d_in, const int* in_sizes, int n_in,
                              void* d_out, int out_size, void* d_ws, size_t ws_size,
                              hipStream_t stream)
{
    const float* q  = (const float*)d_in[0];
    const float* k  = (const float*)d_in[1];
    const float* v  = (const float*)d_in[2];
    const float* Wq = (const float*)d_in[3];
    const float* bq = (const float*)d_in[4];
    const float* Wk = (const float*)d_in[5];
    const float* bk = (const float*)d_in[6];
    const float* Wv = (const float*)d_in[7];
    const float* bv = (const float*)d_in[8];
    const float* Wc = (const float*)d_in[9];
    const float* bc = (const float*)d_in[10];

    float* out  = (float*)d_out;
    float* attn = out + (size_t)BSROWS * D_MODEL;

    // ws layout (~30.1 MB): Wbf[4] | Qw | Kw | Vw(->Ob) | Vt | invz
    short* Wbf  = (short*)d_ws;
    short* Qw   = Wbf + (size_t)4 * WELEMS;
    short* Kw   = Qw + (size_t)BSROWS * D_MODEL;
    short* VwOb = Kw + (size_t)BSROWS * D_MODEL;   // Vw, then reused as Ob
    short* Vt   = VwOb + (size_t)BSROWS * D_MODEL;
    float* invz = (float*)(Vt + (size_t)BSROWS * D_MODEL);

    prep_w<<<dim3(288, 4), dim3(256), 0, stream>>>(Wq, Wk, Wv, Wc, Wbf);

    gemm_qkv<<<dim3(576), dim3(256), 0, stream>>>(q, k, v, Wbf, bq, bk, bv,
                                                  Qw, Kw, VwOb);

    vtrans<<<dim3(32, 24), dim3(256), 0, stream>>>(VwOb, Vt);

    attn_a<<<dim3(768), dim3(128), 0, stream>>>(Qw, Kw, Vt, VwOb /*Ob*/, invz);

    gemm_out<<<dim3(192), dim3(256), 0, stream>>>(VwOb /*Ob*/, Wbf + (size_t)3 * WELEMS,
                                                  bc, out);

    attn_b<<<dim3(768), dim3(128), 0, stream>>>(Qw, Kw, invz, attn);
}

// Round 5
// 257.169 us; speedup vs baseline: 1.1650x; 1.0211x over previous
//
#include <hip/hip_runtime.h>
#include <hip/hip_bf16.h>

// Shapes (fixed): B=2, S=2048, D=768, H=12, DK=64.
// Reference quirks (faithful): heads split the flat (S*D) buffer => head slab
// pointer = base + bh*S*DK (slab indexed by head-local position sigma, NOT by
// global s); PV uses PRE-softmax score; attn (softmax) is a second output
// concatenated after out in d_out.

#define S_LEN   2048
#define D_MODEL 768
#define NHEAD   12
#define DKH     64
#define BSROWS  4096            // B*S
#define HEADSZ  (S_LEN * DKH)   // 131072 elements per (b,h) head slab
#define WELEMS  (D_MODEL * D_MODEL)   // 589824

typedef __attribute__((ext_vector_type(4))) float f32x4;
typedef __attribute__((ext_vector_type(8))) short s16x8;

static __device__ __forceinline__ short f2bf(float f) {
    union { float f; unsigned u; } x; x.f = f;
    unsigned r = x.u + 0x7fffu + ((x.u >> 16) & 1u);   // RNE
    return (short)(unsigned short)(r >> 16);
}

static __device__ __forceinline__ s16x8 cvt8(f32x4 a, f32x4 b) {
    s16x8 o;
    o[0] = f2bf(a[0]); o[1] = f2bf(a[1]); o[2] = f2bf(a[2]); o[3] = f2bf(a[3]);
    o[4] = f2bf(b[0]); o[5] = f2bf(b[1]); o[6] = f2bf(b[2]); o[7] = f2bf(b[3]);
    return o;
}

// async global->LDS, 16B/lane; lds dest must be wave-uniform (HW adds lane*16)
static __device__ __forceinline__ void gload16(const void* g, void* l) {
    __builtin_amdgcn_global_load_lds((const __attribute__((address_space(1))) void*)g,
                                     (__attribute__((address_space(3))) void*)l, 16, 0, 0);
}

// Swizzled fragment read from a [rows][64] bf16 tile (128B rows; chunks were
// stored at (c ^ (row&7))). c16 = 16B-chunk index 0..7.
static __device__ __forceinline__ s16x8 ldfrag(const short* tile, int row, int c16) {
    int byte = row * 128 + ((c16 * 16) ^ ((row & 7) << 4));
    return *(const s16x8*)((const char*)tile + byte);
}

// ---------------------------------------------------------------------------
// W f32 -> bf16 prepass (4 matrices of 768x768)
// ---------------------------------------------------------------------------
__global__ __launch_bounds__(256) void prep_w(const float* __restrict__ W0,
                                              const float* __restrict__ W1,
                                              const float* __restrict__ W2,
                                              const float* __restrict__ W3,
                                              short* __restrict__ dst)
{
    const float* src = (blockIdx.y == 0) ? W0 : (blockIdx.y == 1) ? W1
                     : (blockIdx.y == 2) ? W2 : W3;
    short* d = dst + (size_t)blockIdx.y * WELEMS;
    int i = (blockIdx.x * 256 + threadIdx.x) * 8;
    f32x4 a = *(const f32x4*)(src + i);
    f32x4 b = *(const f32x4*)(src + i + 4);
    *(s16x8*)(d + i) = cvt8(a, b);
}

// ---------------------------------------------------------------------------
// GEMM 128x128 tile, BK=64, 256 threads = 4 waves (2x2), each wave 64x64.
// OUT_MODE: 0 = bf16 row-major, 1 = f32 row-major, 2 = bf16 Vt-transposed
// head-slab layout Vt[bh][dk][sigma] with the FAITHFUL flat head split:
// flat f = s*768+col; head = f/131072; sigma = (f%131072)/64; dk = col&63.
// Equivalently u = s*12 + (col>>6): head = u>>11, sigma = u&2047.
// ---------------------------------------------------------------------------
template<int A_F32, int OUT_MODE>
static __device__ __forceinline__ void gemm_body128(const void* __restrict__ Av,
                                                    const short* __restrict__ Wb,
                                                    const float* __restrict__ bias,
                                                    void* __restrict__ Cv,
                                                    int mt, int nt)
{
    __shared__ short As[8192];   // [128][64] swizzled
    __shared__ short Bs[8192];
    const int t = threadIdx.x, w = t >> 6, lane = t & 63;
    const int lrow = lane & 15, lgrp = lane >> 4;
    const int wr = w >> 1, wc = w & 1;

    f32x4 acc[4][4];
#pragma unroll
    for (int m = 0; m < 4; ++m)
#pragma unroll
        for (int n = 0; n < 4; ++n) acc[m][n] = {0.f, 0.f, 0.f, 0.f};

    for (int kk = 0; kk < 768; kk += 64) {
        __syncthreads();
#pragma unroll
        for (int j = 0; j < 4; ++j) {              // B tile: 16KB via gload
            int cid = t + j * 256, row = cid >> 3, ch = cid & 7;
            gload16(Wb + (size_t)(nt * 128 + row) * 768 + kk + ((ch ^ (row & 7)) * 8),
                    (char*)Bs + j * 4096 + w * 1024);
        }
        if (A_F32) {
#pragma unroll
            for (int j = 0; j < 2; ++j) {          // A tile: f32 -> bf16 regs -> LDS
                int cid = t + j * 256, row = cid >> 2, q4 = cid & 3;
                const float* src = (const float*)Av + (size_t)(mt * 128 + row) * 768 + kk + q4 * 16;
                f32x4 v0 = *(const f32x4*)(src);
                f32x4 v1 = *(const f32x4*)(src + 4);
                f32x4 v2 = *(const f32x4*)(src + 8);
                f32x4 v3 = *(const f32x4*)(src + 12);
                int c0 = q4 * 2;
                *(s16x8*)((char*)As + row * 128 + (((c0    ) ^ (row & 7)) * 16)) = cvt8(v0, v1);
                *(s16x8*)((char*)As + row * 128 + (((c0 + 1) ^ (row & 7)) * 16)) = cvt8(v2, v3);
            }
        } else {
#pragma unroll
            for (int j = 0; j < 4; ++j) {
                int cid = t + j * 256, row = cid >> 3, ch = cid & 7;
                gload16((const short*)Av + (size_t)(mt * 128 + row) * 768 + kk + ((ch ^ (row & 7)) * 8),
                        (char*)As + j * 4096 + w * 1024);
            }
        }
        __syncthreads();
#pragma unroll
        for (int kc = 0; kc < 2; ++kc) {
            s16x8 af[4], bfr[4];
#pragma unroll
            for (int m = 0; m < 4; ++m) af[m] = ldfrag(As, wr * 64 + m * 16 + lrow, kc * 4 + lgrp);
#pragma unroll
            for (int n = 0; n < 4; ++n) bfr[n] = ldfrag(Bs, wc * 64 + n * 16 + lrow, kc * 4 + lgrp);
            __builtin_amdgcn_s_setprio(1);
#pragma unroll
            for (int m = 0; m < 4; ++m)
#pragma unroll
                for (int n = 0; n < 4; ++n)
                    acc[m][n] = __builtin_amdgcn_mfma_f32_16x16x32_bf16(af[m], bfr[n], acc[m][n], 0, 0, 0);
            __builtin_amdgcn_s_setprio(0);
        }
    }
#pragma unroll
    for (int n = 0; n < 4; ++n) {
        int col = nt * 128 + wc * 64 + n * 16 + lrow;
        float bvv = bias[col];
        if (OUT_MODE == 2) {
            int c6 = col >> 6, dk = col & 63;
#pragma unroll
            for (int m = 0; m < 4; ++m)
#pragma unroll
                for (int r = 0; r < 4; ++r) {
                    int grow = mt * 128 + wr * 64 + m * 16 + lgrp * 4 + r;   // 0..4095
                    int bb = grow >> 11, s = grow & 2047;
                    int u = s * NHEAD + c6;                 // flat/64 within b
                    int hh = u >> 11, sig = u & 2047;       // faithful head split
                    ((short*)Cv)[(((size_t)(bb * NHEAD + hh)) << 17)
                                 + ((size_t)dk << 11) + sig]
                        = f2bf(acc[m][n][r] + bvv);
                }
        } else {
#pragma unroll
            for (int m = 0; m < 4; ++m)
#pragma unroll
                for (int r = 0; r < 4; ++r) {
                    int row = mt * 128 + wr * 64 + m * 16 + lgrp * 4 + r;
                    float v = acc[m][n][r] + bvv;
                    if (OUT_MODE == 1) ((float*)Cv)[(size_t)row * 768 + col] = v;
                    else               ((short*)Cv)[(size_t)row * 768 + col] = f2bf(v);
                }
        }
    }
}

// QKV fused: 576 blocks 1-D; panel-chunked XCD swizzle so the 6 nt-blocks of
// an A-panel run on one XCD.  z==2 (V) writes the transposed head-slab layout
// directly (replaces the vtrans kernel).
__global__ __launch_bounds__(256) void gemm_qkv(const float* __restrict__ q,
                                                const float* __restrict__ k,
                                                const float* __restrict__ v,
                                                const short* __restrict__ Wbf,
                                                const float* __restrict__ bq,
                                                const float* __restrict__ bk,
                                                const float* __restrict__ bv,
                                                short* __restrict__ Qw,
                                                short* __restrict__ Kw,
                                                short* __restrict__ Vt)
{
    const int bid = blockIdx.x;
    const int idx = bid >> 3;
    const int panel = (bid & 7) * 12 + idx / 6;    // 96 panels = 32 mt x 3 z
    const int nt = idx % 6;
    const int z = panel / 32, mt = panel % 32;
    if (z == 0)
        gemm_body128<1, 0>(q, Wbf, bq, Qw, mt, nt);
    else if (z == 1)
        gemm_body128<1, 0>(k, Wbf + (size_t)WELEMS, bk, Kw, mt, nt);
    else
        gemm_body128<1, 2>(v, Wbf + (size_t)2 * WELEMS, bv, Vt, mt, nt);
}

__global__ __launch_bounds__(256) void gemm_out(const short* __restrict__ Ob,
                                                const short* __restrict__ Wcb,
                                                const float* __restrict__ bc,
                                                float* __restrict__ out)
{
    const int bid = blockIdx.x;
    const int idx = bid >> 3;
    const int panel = (bid & 7) * 4 + idx / 6;     // 32 panels
    const int nt = idx % 6;
    gemm_body128<0, 1>(Ob, Wcb, bc, out, panel, nt);
}

// ---------------------------------------------------------------------------
// Fused attention (pass A + pass B in one kernel).  128 threads = 2 waves,
// each wave owns 32 q-rows of a 64-row q-block.
// Pass A: QK^T -> Z partials + PV with RAW score (reference bug) -> Ob.
// Pass B: recompute QK^T with swapped operands, write attn = exp(s)*invz
// as f32x4 stores; K ring-buffered 4 deep, one barrier per 2 k-tiles.
// ---------------------------------------------------------------------------
__global__ __launch_bounds__(128) void attn_fused2(const short* __restrict__ Qb,
                                                   const short* __restrict__ Kb,
                                                   const short* __restrict__ Vtb,
                                                   short* __restrict__ Ob,
                                                   float* __restrict__ attn)
{
    __shared__ short lds[24576];        // 48 KB
    short* Qs = lds;                    // [64][64] swizzled (4096)
    // K dbuf: lds+4096 + buf*4096 ; V dbuf: lds+12288 + buf*4096
    // strips: lds+20480 + w*2048 ; pass-B K ring: lds+4096 + slot*4096
    float* fvz = (float*)lds;           // invz handoff (Qs dead after frag load)

    const int bid = blockIdx.x;
    const int swz = (bid & 7) * 96 + (bid >> 3);    // XCD-contiguous heads
    const int qb = swz & 31, bh = swz >> 5;
    const int t = threadIdx.x, w = t >> 6, lane = t & 63;
    const int lrow = lane & 15, lgrp = lane >> 4;
    const int b = bh / NHEAD, h = bh % NHEAD;
    const short* Qh = Qb + (size_t)bh * HEADSZ;
    const short* Kh = Kb + (size_t)bh * HEADSZ;
    const short* Vth = Vtb + (size_t)bh * HEADSZ;   // [64 dk][2048 sigma]
    const int q0 = qb * 64;

#define STAGE_K4(dst, kt) do {                                                  \
    _Pragma("unroll")                                                           \
    for (int j = 0; j < 4; ++j) {                                               \
        int cid = t + j * 128, row = cid >> 3, ch = cid & 7;                    \
        gload16(Kh + (size_t)((kt) * 64 + row) * DKH + ((ch ^ (row & 7)) * 8),  \
                (dst) + w * 512 + j * 1024);                                    \
    } } while (0)

#define STAGE_V4(dst, kt) do {                                                  \
    _Pragma("unroll")                                                           \
    for (int j = 0; j < 4; ++j) {                                               \
        int cid = t + j * 128, row = cid >> 3, ch = cid & 7;                    \
        gload16(Vth + (size_t)row * S_LEN + (kt) * 64 + ((ch ^ (row & 7)) * 8), \
                (dst) + w * 512 + j * 1024);                                    \
    } } while (0)

    // Stage Q (once) + first K/V tile.
#pragma unroll
    for (int j = 0; j < 4; ++j) {
        int cid = t + j * 128, row = cid >> 3, ch = cid & 7;
        gload16(Qh + (size_t)(q0 + row) * DKH + ((ch ^ (row & 7)) * 8),
                Qs + w * 512 + j * 1024);
    }
    STAGE_K4(lds + 4096, 0);
    STAGE_V4(lds + 12288, 0);
    __syncthreads();

    s16x8 aq[2][2];
#pragma unroll
    for (int m = 0; m < 2; ++m)
#pragma unroll
        for (int c = 0; c < 2; ++c)
            aq[m][c] = ldfrag(Qs, w * 32 + m * 16 + lrow, c * 4 + lgrp);

    f32x4 pv[2][4];
#pragma unroll
    for (int m = 0; m < 2; ++m)
#pragma unroll
        for (int n = 0; n < 4; ++n) pv[m][n] = {0.f, 0.f, 0.f, 0.f};
    float zp[2][4] = {{0.f,0.f,0.f,0.f},{0.f,0.f,0.f,0.f}};

    short* SW = lds + 20480 + w * 2048;
    int cur = 0;

    // ---- Pass A ----
    for (int kt = 0; kt < 32; ++kt) {
        if (kt) __syncthreads();
        if (kt < 31) {
            STAGE_K4(lds + 4096 + (cur ^ 1) * 4096, kt + 1);
            STAGE_V4(lds + 12288 + (cur ^ 1) * 4096, kt + 1);
        }
        const short* Kc = lds + 4096 + cur * 4096;
        const short* Vc = lds + 12288 + cur * 4096;

#pragma unroll
        for (int n = 0; n < 4; ++n) {
            f32x4 s0 = {0.f,0.f,0.f,0.f}, s1 = {0.f,0.f,0.f,0.f};
            __builtin_amdgcn_s_setprio(1);
#pragma unroll
            for (int c = 0; c < 2; ++c) {
                s16x8 bk = ldfrag(Kc, n * 16 + lrow, c * 4 + lgrp);
                s0 = __builtin_amdgcn_mfma_f32_16x16x32_bf16(aq[0][c], bk, s0, 0, 0, 0);
                s1 = __builtin_amdgcn_mfma_f32_16x16x32_bf16(aq[1][c], bk, s1, 0, 0, 0);
            }
            __builtin_amdgcn_s_setprio(0);
            int kcol2 = (n * 16 + lrow) * 2;
#pragma unroll
            for (int r = 0; r < 4; ++r) {
                float v0 = s0[r] * 0.125f, v1 = s1[r] * 0.125f;
                zp[0][r] += __expf(v0);
                zp[1][r] += __expf(v1);
                int qa = lgrp * 4 + r, qb2 = 16 + qa;
                *(short*)((char*)SW + qa * 128 + (kcol2 ^ ((qa & 7) << 4))) = f2bf(v0);
                *(short*)((char*)SW + qb2 * 128 + (kcol2 ^ ((qb2 & 7) << 4))) = f2bf(v1);
            }
        }
        s16x8 as[2][2];
#pragma unroll
        for (int m = 0; m < 2; ++m)
#pragma unroll
            for (int c = 0; c < 2; ++c)
                as[m][c] = ldfrag(SW, m * 16 + lrow, c * 4 + lgrp);
        __builtin_amdgcn_s_setprio(1);
#pragma unroll
        for (int n = 0; n < 4; ++n) {
#pragma unroll
            for (int c = 0; c < 2; ++c) {
                s16x8 bv = ldfrag(Vc, n * 16 + lrow, c * 4 + lgrp);
                pv[0][n] = __builtin_amdgcn_mfma_f32_16x16x32_bf16(as[0][c], bv, pv[0][n], 0, 0, 0);
                pv[1][n] = __builtin_amdgcn_mfma_f32_16x16x32_bf16(as[1][c], bv, pv[1][n], 0, 0, 0);
            }
        }
        __builtin_amdgcn_s_setprio(0);
        cur ^= 1;
    }

    // Z reduce over the 16 lanes of each row group; park invz in LDS (Qs area,
    // dead since the fragment loads; NOT the strip area).
#pragma unroll
    for (int m = 0; m < 2; ++m)
#pragma unroll
        for (int r = 0; r < 4; ++r) {
            float z = zp[m][r];
            z += __shfl_xor(z, 1, 16);
            z += __shfl_xor(z, 2, 16);
            z += __shfl_xor(z, 4, 16);
            z += __shfl_xor(z, 8, 16);
            if (lrow == 0)
                fvz[w * 32 + m * 16 + lgrp * 4 + r] = 1.0f / z;
        }
    __syncthreads();     // invz visible; all waves past PV -> K/V dbuf free

    // Pass-B prologue: stage ring slots 0,1 (they fly under the Ob epilogue).
    STAGE_K4(lds + 4096, 0);
    STAGE_K4(lds + 8192, 1);

    // PV epilogue -> Ob (bf16, concat layout out[b][sigma][h*64+dk]).
#pragma unroll
    for (int m = 0; m < 2; ++m)
#pragma unroll
        for (int n = 0; n < 4; ++n)
#pragma unroll
            for (int r = 0; r < 4; ++r) {
                int srow = q0 + w * 32 + m * 16 + lgrp * 4 + r;
                Ob[((size_t)b * S_LEN + srow) * D_MODEL + h * DKH + n * 16 + lrow]
                    = f2bf(pv[m][n][r]);
            }

    float invzq[2];
#pragma unroll
    for (int m = 0; m < 2; ++m)
        invzq[m] = fvz[w * 32 + m * 16 + lrow];

    // ---- Pass B: 4-deep K ring, one barrier per 2 k-tiles ----
    float* aw = attn + (size_t)bh * S_LEN * S_LEN;
    for (int kt2 = 0; kt2 < 32; kt2 += 2) {
        __syncthreads();                     // slots kt2, kt2+1 ready
        if (kt2 + 2 < 32) {
            STAGE_K4(lds + 4096 + ((kt2 + 2) & 3) * 4096, kt2 + 2);
            STAGE_K4(lds + 4096 + ((kt2 + 3) & 3) * 4096, kt2 + 3);
        }
#pragma unroll
        for (int u = 0; u < 2; ++u) {
            const int kt = kt2 + u;
            const short* Kc = lds + 4096 + (kt & 3) * 4096;
#pragma unroll
            for (int n = 0; n < 4; ++n) {
                f32x4 s0 = {0.f,0.f,0.f,0.f}, s1 = {0.f,0.f,0.f,0.f};
                __builtin_amdgcn_s_setprio(1);
#pragma unroll
                for (int c = 0; c < 2; ++c) {
                    s16x8 bk = ldfrag(Kc, n * 16 + lrow, c * 4 + lgrp);
                    s0 = __builtin_amdgcn_mfma_f32_16x16x32_bf16(bk, aq[0][c], s0, 0, 0, 0);
                    s1 = __builtin_amdgcn_mfma_f32_16x16x32_bf16(bk, aq[1][c], s1, 0, 0, 0);
                }
                __builtin_amdgcn_s_setprio(0);
                f32x4 a0, a1;
#pragma unroll
                for (int r = 0; r < 4; ++r) {
                    a0[r] = __expf(s0[r] * 0.125f) * invzq[0];
                    a1[r] = __expf(s1[r] * 0.125f) * invzq[1];
                }
                int kbase = kt * 64 + n * 16 + lgrp * 4;
                *(f32x4*)(aw + (size_t)(q0 + w * 32 + lrow) * S_LEN + kbase) = a0;
                *(f32x4*)(aw + (size_t)(q0 + w * 32 + 16 + lrow) * S_LEN + kbase) = a1;
            }
        }
    }
#undef STAGE_K4
#undef STAGE_V4
}

// ---------------------------------------------------------------------------
extern "C" void kernel_launch(void* const* d_in, const int* in_sizes, int n_in,
                              void* d_out, int out_size, void* d_ws, size_t ws_size,
                              hipStream_t stream)
{
    const float* q  = (const float*)d_in[0];
    const float* k  = (const float*)d_in[1];
    const float* v  = (const float*)d_in[2];
    const float* Wq = (const float*)d_in[3];
    const float* bq = (const float*)d_in[4];
    const float* Wk = (const float*)d_in[5];
    const float* bk = (const float*)d_in[6];
    const float* Wv = (const float*)d_in[7];
    const float* bv = (const float*)d_in[8];
    const float* Wc = (const float*)d_in[9];
    const float* bc = (const float*)d_in[10];

    float* out  = (float*)d_out;
    float* attn = out + (size_t)BSROWS * D_MODEL;

    // ws layout (~29.8 MB): Wbf[4] | Qw | Kw | Ob | Vt
    short* Wbf = (short*)d_ws;
    short* Qw  = Wbf + (size_t)4 * WELEMS;
    short* Kw  = Qw + (size_t)BSROWS * D_MODEL;
    short* Ob  = Kw + (size_t)BSROWS * D_MODEL;
    short* Vt  = Ob + (size_t)BSROWS * D_MODEL;    // [24][64][2048] bf16

    prep_w<<<dim3(288, 4), dim3(256), 0, stream>>>(Wq, Wk, Wv, Wc, Wbf);

    gemm_qkv<<<dim3(576), dim3(256), 0, stream>>>(q, k, v, Wbf, bq, bk, bv,
                                                  Qw, Kw, Vt);

    attn_fused2<<<dim3(768), dim3(128), 0, stream>>>(Qw, Kw, Vt, Ob, attn);

    gemm_out<<<dim3(192), dim3(256), 0, stream>>>(Ob, Wbf + (size_t)3 * WELEMS,
                                                  bc, out);
}

// Round 6
// 245.990 us; speedup vs baseline: 1.2179x; 1.0454x over previous
//
#include <hip/hip_runtime.h>
#include <hip/hip_bf16.h>

// Shapes (fixed): B=2, S=2048, D=768, H=12, DK=64.
// Reference quirks (faithful): heads split the flat (S*D) buffer => head slab
// pointer = base + bh*S*DK (slab indexed by head-local position sigma, NOT by
// global s); PV uses PRE-softmax score; attn (softmax) is a second output
// concatenated after out in d_out.

#define S_LEN   2048
#define D_MODEL 768
#define NHEAD   12
#define DKH     64
#define BSROWS  4096            // B*S
#define HEADSZ  (S_LEN * DKH)   // 131072 elements per (b,h) head slab
#define WELEMS  (D_MODEL * D_MODEL)   // 589824

typedef __attribute__((ext_vector_type(4))) float f32x4;
typedef __attribute__((ext_vector_type(8))) short s16x8;

static __device__ __forceinline__ short f2bf(float f) {
    union { float f; unsigned u; } x; x.f = f;
    unsigned r = x.u + 0x7fffu + ((x.u >> 16) & 1u);   // RNE
    return (short)(unsigned short)(r >> 16);
}

static __device__ __forceinline__ s16x8 cvt8(f32x4 a, f32x4 b) {
    s16x8 o;
    o[0] = f2bf(a[0]); o[1] = f2bf(a[1]); o[2] = f2bf(a[2]); o[3] = f2bf(a[3]);
    o[4] = f2bf(b[0]); o[5] = f2bf(b[1]); o[6] = f2bf(b[2]); o[7] = f2bf(b[3]);
    return o;
}

// async global->LDS, 16B/lane; lds dest must be wave-uniform (HW adds lane*16)
static __device__ __forceinline__ void gload16(const void* g, void* l) {
    __builtin_amdgcn_global_load_lds((const __attribute__((address_space(1))) void*)g,
                                     (__attribute__((address_space(3))) void*)l, 16, 0, 0);
}

// Swizzled fragment read from a [rows][64] bf16 tile (128B rows; chunks were
// stored at (c ^ (row&7))). c16 = 16B-chunk index 0..7.
static __device__ __forceinline__ s16x8 ldfrag(const short* tile, int row, int c16) {
    int byte = row * 128 + ((c16 * 16) ^ ((row & 7) << 4));
    return *(const s16x8*)((const char*)tile + byte);
}

// ---------------------------------------------------------------------------
// W f32 -> bf16 prepass (4 matrices of 768x768)
// ---------------------------------------------------------------------------
__global__ __launch_bounds__(256) void prep_w(const float* __restrict__ W0,
                                              const float* __restrict__ W1,
                                              const float* __restrict__ W2,
                                              const float* __restrict__ W3,
                                              short* __restrict__ dst)
{
    const float* src = (blockIdx.y == 0) ? W0 : (blockIdx.y == 1) ? W1
                     : (blockIdx.y == 2) ? W2 : W3;
    short* d = dst + (size_t)blockIdx.y * WELEMS;
    int i = (blockIdx.x * 256 + threadIdx.x) * 8;
    f32x4 a = *(const f32x4*)(src + i);
    f32x4 b = *(const f32x4*)(src + i + 4);
    *(s16x8*)(d + i) = cvt8(a, b);
}

// ---------------------------------------------------------------------------
// GEMM 128x128 tile, BK=64, 256 threads = 4 waves (2x2), each wave 64x64.
// OUT_MODE: 0 = bf16 row-major, 1 = f32 row-major, 2 = bf16 Vt-transposed
// head-slab layout Vt[bh][dk][sigma] with the FAITHFUL flat head split:
// u = s*12 + (col>>6): head = u>>11, sigma = u&2047, dk = col&63.
// ---------------------------------------------------------------------------
template<int A_F32, int OUT_MODE>
static __device__ __forceinline__ void gemm_body128(const void* __restrict__ Av,
                                                    const short* __restrict__ Wb,
                                                    const float* __restrict__ bias,
                                                    void* __restrict__ Cv,
                                                    int mt, int nt)
{
    __shared__ short As[8192];   // [128][64] swizzled
    __shared__ short Bs[8192];
    const int t = threadIdx.x, w = t >> 6, lane = t & 63;
    const int lrow = lane & 15, lgrp = lane >> 4;
    const int wr = w >> 1, wc = w & 1;

    f32x4 acc[4][4];
#pragma unroll
    for (int m = 0; m < 4; ++m)
#pragma unroll
        for (int n = 0; n < 4; ++n) acc[m][n] = {0.f, 0.f, 0.f, 0.f};

    for (int kk = 0; kk < 768; kk += 64) {
        __syncthreads();
#pragma unroll
        for (int j = 0; j < 4; ++j) {              // B tile: 16KB via gload
            int cid = t + j * 256, row = cid >> 3, ch = cid & 7;
            gload16(Wb + (size_t)(nt * 128 + row) * 768 + kk + ((ch ^ (row & 7)) * 8),
                    (char*)Bs + j * 4096 + w * 1024);
        }
        if (A_F32) {
#pragma unroll
            for (int j = 0; j < 2; ++j) {          // A tile: f32 -> bf16 regs -> LDS
                int cid = t + j * 256, row = cid >> 2, q4 = cid & 3;
                const float* src = (const float*)Av + (size_t)(mt * 128 + row) * 768 + kk + q4 * 16;
                f32x4 v0 = *(const f32x4*)(src);
                f32x4 v1 = *(const f32x4*)(src + 4);
                f32x4 v2 = *(const f32x4*)(src + 8);
                f32x4 v3 = *(const f32x4*)(src + 12);
                int c0 = q4 * 2;
                *(s16x8*)((char*)As + row * 128 + (((c0    ) ^ (row & 7)) * 16)) = cvt8(v0, v1);
                *(s16x8*)((char*)As + row * 128 + (((c0 + 1) ^ (row & 7)) * 16)) = cvt8(v2, v3);
            }
        } else {
#pragma unroll
            for (int j = 0; j < 4; ++j) {
                int cid = t + j * 256, row = cid >> 3, ch = cid & 7;
                gload16((const short*)Av + (size_t)(mt * 128 + row) * 768 + kk + ((ch ^ (row & 7)) * 8),
                        (char*)As + j * 4096 + w * 1024);
            }
        }
        __syncthreads();
#pragma unroll
        for (int kc = 0; kc < 2; ++kc) {
            s16x8 af[4], bfr[4];
#pragma unroll
            for (int m = 0; m < 4; ++m) af[m] = ldfrag(As, wr * 64 + m * 16 + lrow, kc * 4 + lgrp);
#pragma unroll
            for (int n = 0; n < 4; ++n) bfr[n] = ldfrag(Bs, wc * 64 + n * 16 + lrow, kc * 4 + lgrp);
            __builtin_amdgcn_s_setprio(1);
#pragma unroll
            for (int m = 0; m < 4; ++m)
#pragma unroll
                for (int n = 0; n < 4; ++n)
                    acc[m][n] = __builtin_amdgcn_mfma_f32_16x16x32_bf16(af[m], bfr[n], acc[m][n], 0, 0, 0);
            __builtin_amdgcn_s_setprio(0);
        }
    }
#pragma unroll
    for (int n = 0; n < 4; ++n) {
        int col = nt * 128 + wc * 64 + n * 16 + lrow;
        float bvv = bias[col];
        if (OUT_MODE == 2) {
            int c6 = col >> 6, dk = col & 63;
#pragma unroll
            for (int m = 0; m < 4; ++m)
#pragma unroll
                for (int r = 0; r < 4; ++r) {
                    int grow = mt * 128 + wr * 64 + m * 16 + lgrp * 4 + r;   // 0..4095
                    int bb = grow >> 11, s = grow & 2047;
                    int u = s * NHEAD + c6;                 // flat/64 within b
                    int hh = u >> 11, sig = u & 2047;       // faithful head split
                    ((short*)Cv)[(((size_t)(bb * NHEAD + hh)) << 17)
                                 + ((size_t)dk << 11) + sig]
                        = f2bf(acc[m][n][r] + bvv);
                }
        } else {
#pragma unroll
            for (int m = 0; m < 4; ++m)
#pragma unroll
                for (int r = 0; r < 4; ++r) {
                    int row = mt * 128 + wr * 64 + m * 16 + lgrp * 4 + r;
                    float v = acc[m][n][r] + bvv;
                    if (OUT_MODE == 1) ((float*)Cv)[(size_t)row * 768 + col] = v;
                    else               ((short*)Cv)[(size_t)row * 768 + col] = f2bf(v);
                }
        }
    }
}

// QKV fused: 576 blocks 1-D; panel-chunked XCD swizzle so the 6 nt-blocks of
// an A-panel run on one XCD.  z==2 (V) writes the transposed head-slab layout
// directly.
__global__ __launch_bounds__(256) void gemm_qkv(const float* __restrict__ q,
                                                const float* __restrict__ k,
                                                const float* __restrict__ v,
                                                const short* __restrict__ Wbf,
                                                const float* __restrict__ bq,
                                                const float* __restrict__ bk,
                                                const float* __restrict__ bv,
                                                short* __restrict__ Qw,
                                                short* __restrict__ Kw,
                                                short* __restrict__ Vt)
{
    const int bid = blockIdx.x;
    const int idx = bid >> 3;
    const int panel = (bid & 7) * 12 + idx / 6;    // 96 panels = 32 mt x 3 z
    const int nt = idx % 6;
    const int z = panel / 32, mt = panel % 32;
    if (z == 0)
        gemm_body128<1, 0>(q, Wbf, bq, Qw, mt, nt);
    else if (z == 1)
        gemm_body128<1, 0>(k, Wbf + (size_t)WELEMS, bk, Kw, mt, nt);
    else
        gemm_body128<1, 2>(v, Wbf + (size_t)2 * WELEMS, bv, Vt, mt, nt);
}

__global__ __launch_bounds__(256) void gemm_out(const short* __restrict__ Ob,
                                                const short* __restrict__ Wcb,
                                                const float* __restrict__ bc,
                                                float* __restrict__ out)
{
    const int bid = blockIdx.x;
    const int idx = bid >> 3;
    const int panel = (bid & 7) * 4 + idx / 6;     // 32 panels
    const int nt = idx % 6;
    gemm_body128<0, 1>(Ob, Wcb, bc, out, panel, nt);
}

// ---------------------------------------------------------------------------
// Fused attention, 256 threads = 4 waves, each wave owns 16 q-rows of a
// 64-row q-block (R6: was 2 waves x 32 rows -> TLP 2x, per-CU totals equal).
// Pass A: QK^T -> Z partials + PV with RAW score (reference bug) -> Ob.
// Pass B: recompute QK^T swapped, write attn = exp(s)*invz as f32x4;
// K ring 4 deep, one barrier per 2 k-tiles.
// LDS map (shorts): Q 0-4095 | Kbuf 4096+b*4096 | Vbuf 12288+b*4096 |
// strips 20480 + w*1024.  fvz aliases Q region (dead after frag loads).
// ---------------------------------------------------------------------------
__global__ __launch_bounds__(256) void attn_fused2(const short* __restrict__ Qb,
                                                   const short* __restrict__ Kb,
                                                   const short* __restrict__ Vtb,
                                                   short* __restrict__ Ob,
                                                   float* __restrict__ attn)
{
    __shared__ short lds[24576];        // 48 KB
    short* Qs = lds;
    float* fvz = (float*)lds;

    const int bid = blockIdx.x;
    const int swz = (bid & 7) * 96 + (bid >> 3);    // XCD-contiguous heads
    const int qb = swz & 31, bh = swz >> 5;
    const int t = threadIdx.x, w = t >> 6, lane = t & 63;
    const int lrow = lane & 15, lgrp = lane >> 4;
    const int b = bh / NHEAD, h = bh % NHEAD;
    const short* Qh = Qb + (size_t)bh * HEADSZ;
    const short* Kh = Kb + (size_t)bh * HEADSZ;
    const short* Vth = Vtb + (size_t)bh * HEADSZ;   // [64 dk][2048 sigma]
    const int q0 = qb * 64;

// 256-thread staging: j=0..1, wave w covers rows w*8+j*32 (+lane>>3), 16B/lane
#define STAGE_K4(dst, kt) do {                                                  \
    _Pragma("unroll")                                                           \
    for (int j = 0; j < 2; ++j) {                                               \
        int cid = t + j * 256, row = cid >> 3, ch = cid & 7;                    \
        gload16(Kh + (size_t)((kt) * 64 + row) * DKH + ((ch ^ (row & 7)) * 8),  \
                (dst) + w * 512 + j * 2048);                                    \
    } } while (0)

#define STAGE_V4(dst, kt) do {                                                  \
    _Pragma("unroll")                                                           \
    for (int j = 0; j < 2; ++j) {                                               \
        int cid = t + j * 256, row = cid >> 3, ch = cid & 7;                    \
        gload16(Vth + (size_t)row * S_LEN + (kt) * 64 + ((ch ^ (row & 7)) * 8), \
                (dst) + w * 512 + j * 2048);                                    \
    } } while (0)

    // Stage Q (once) + first K/V tile.
#pragma unroll
    for (int j = 0; j < 2; ++j) {
        int cid = t + j * 256, row = cid >> 3, ch = cid & 7;
        gload16(Qh + (size_t)(q0 + row) * DKH + ((ch ^ (row & 7)) * 8),
                Qs + w * 512 + j * 2048);
    }
    STAGE_K4(lds + 4096, 0);
    STAGE_V4(lds + 12288, 0);
    __syncthreads();

    s16x8 aq[2];
#pragma unroll
    for (int c = 0; c < 2; ++c)
        aq[c] = ldfrag(Qs, w * 16 + lrow, c * 4 + lgrp);

    f32x4 pv[4];
#pragma unroll
    for (int n = 0; n < 4; ++n) pv[n] = {0.f, 0.f, 0.f, 0.f};
    float zp[4] = {0.f, 0.f, 0.f, 0.f};

    short* SW = lds + 20480 + w * 1024;   // [16 q][64 k] swizzled strip
    int cur = 0;

    // ---- Pass A ----
    for (int kt = 0; kt < 32; ++kt) {
        if (kt) __syncthreads();
        if (kt < 31) {
            STAGE_K4(lds + 4096 + (cur ^ 1) * 4096, kt + 1);
            STAGE_V4(lds + 12288 + (cur ^ 1) * 4096, kt + 1);
        }
        const short* Kc = lds + 4096 + cur * 4096;
        const short* Vc = lds + 12288 + cur * 4096;

#pragma unroll
        for (int n = 0; n < 4; ++n) {
            f32x4 s = {0.f, 0.f, 0.f, 0.f};
            __builtin_amdgcn_s_setprio(1);
#pragma unroll
            for (int c = 0; c < 2; ++c) {
                s16x8 bk = ldfrag(Kc, n * 16 + lrow, c * 4 + lgrp);
                s = __builtin_amdgcn_mfma_f32_16x16x32_bf16(aq[c], bk, s, 0, 0, 0);
            }
            __builtin_amdgcn_s_setprio(0);
            int kcol2 = (n * 16 + lrow) * 2;
#pragma unroll
            for (int r = 0; r < 4; ++r) {
                float v0 = s[r] * 0.125f;
                zp[r] += __expf(v0);
                int qa = lgrp * 4 + r;
                *(short*)((char*)SW + qa * 128 + (kcol2 ^ ((qa & 7) << 4))) = f2bf(v0);
            }
        }
        s16x8 as[2];
#pragma unroll
        for (int c = 0; c < 2; ++c)
            as[c] = ldfrag(SW, lrow, c * 4 + lgrp);
        __builtin_amdgcn_s_setprio(1);
#pragma unroll
        for (int n = 0; n < 4; ++n) {
#pragma unroll
            for (int c = 0; c < 2; ++c) {
                s16x8 bv = ldfrag(Vc, n * 16 + lrow, c * 4 + lgrp);
                pv[n] = __builtin_amdgcn_mfma_f32_16x16x32_bf16(as[c], bv, pv[n], 0, 0, 0);
            }
        }
        __builtin_amdgcn_s_setprio(0);
        cur ^= 1;
    }

    // Z reduce over the 16 lanes of each row group; park invz in LDS (Q area).
#pragma unroll
    for (int r = 0; r < 4; ++r) {
        float z = zp[r];
        z += __shfl_xor(z, 1, 16);
        z += __shfl_xor(z, 2, 16);
        z += __shfl_xor(z, 4, 16);
        z += __shfl_xor(z, 8, 16);
        if (lrow == 0)
            fvz[w * 16 + lgrp * 4 + r] = 1.0f / z;
    }
    __syncthreads();     // invz visible; all waves past PV -> K/V dbuf free

    // Pass-B prologue: stage ring slots 0,1 (fly under the Ob epilogue).
    STAGE_K4(lds + 4096, 0);
    STAGE_K4(lds + 8192, 1);

    // PV epilogue -> Ob (bf16, concat layout out[b][sigma][h*64+dk]).
#pragma unroll
    for (int n = 0; n < 4; ++n)
#pragma unroll
        for (int r = 0; r < 4; ++r) {
            int srow = q0 + w * 16 + lgrp * 4 + r;
            Ob[((size_t)b * S_LEN + srow) * D_MODEL + h * DKH + n * 16 + lrow]
                = f2bf(pv[n][r]);
        }

    float invzq = fvz[w * 16 + lrow];

    // ---- Pass B: 4-deep K ring, one barrier per 2 k-tiles ----
    float* aw = attn + (size_t)bh * S_LEN * S_LEN;
    for (int kt2 = 0; kt2 < 32; kt2 += 2) {
        __syncthreads();                     // slots kt2, kt2+1 ready
        if (kt2 + 2 < 32) {
            STAGE_K4(lds + 4096 + ((kt2 + 2) & 3) * 4096, kt2 + 2);
            STAGE_K4(lds + 4096 + ((kt2 + 3) & 3) * 4096, kt2 + 3);
        }
#pragma unroll
        for (int u = 0; u < 2; ++u) {
            const int kt = kt2 + u;
            const short* Kc = lds + 4096 + (kt & 3) * 4096;
#pragma unroll
            for (int n = 0; n < 4; ++n) {
                f32x4 s = {0.f, 0.f, 0.f, 0.f};
                __builtin_amdgcn_s_setprio(1);
#pragma unroll
                for (int c = 0; c < 2; ++c) {
                    s16x8 bk = ldfrag(Kc, n * 16 + lrow, c * 4 + lgrp);
                    s = __builtin_amdgcn_mfma_f32_16x16x32_bf16(bk, aq[c], s, 0, 0, 0);
                }
                __builtin_amdgcn_s_setprio(0);
                f32x4 a0;
#pragma unroll
                for (int r = 0; r < 4; ++r)
                    a0[r] = __expf(s[r] * 0.125f) * invzq;
                int kbase = kt * 64 + n * 16 + lgrp * 4;
                *(f32x4*)(aw + (size_t)(q0 + w * 16 + lrow) * S_LEN + kbase) = a0;
            }
        }
    }
#undef STAGE_K4
#undef STAGE_V4
}

// ---------------------------------------------------------------------------
extern "C" void kernel_launch(void* const* d_in, const int* in_sizes, int n_in,
                              void* d_out, int out_size, void* d_ws, size_t ws_size,
                              hipStream_t stream)
{
    const float* q  = (const float*)d_in[0];
    const float* k  = (const float*)d_in[1];
    const float* v  = (const float*)d_in[2];
    const float* Wq = (const float*)d_in[3];
    const float* bq = (const float*)d_in[4];
    const float* Wk = (const float*)d_in[5];
    const float* bk = (const float*)d_in[6];
    const float* Wv = (const float*)d_in[7];
    const float* bv = (const float*)d_in[8];
    const float* Wc = (const float*)d_in[9];
    const float* bc = (const float*)d_in[10];

    float* out  = (float*)d_out;
    float* attn = out + (size_t)BSROWS * D_MODEL;

    // ws layout (~29.8 MB): Wbf[4] | Qw | Kw | Ob | Vt
    short* Wbf = (short*)d_ws;
    short* Qw  = Wbf + (size_t)4 * WELEMS;
    short* Kw  = Qw + (size_t)BSROWS * D_MODEL;
    short* Ob  = Kw + (size_t)BSROWS * D_MODEL;
    short* Vt  = Ob + (size_t)BSROWS * D_MODEL;    // [24][64][2048] bf16

    prep_w<<<dim3(288, 4), dim3(256), 0, stream>>>(Wq, Wk, Wv, Wc, Wbf);

    gemm_qkv<<<dim3(576), dim3(256), 0, stream>>>(q, k, v, Wbf, bq, bk, bv,
                                                  Qw, Kw, Vt);

    attn_fused2<<<dim3(768), dim3(256), 0, stream>>>(Qw, Kw, Vt, Ob, attn);

    gemm_out<<<dim3(192), dim3(256), 0, stream>>>(Ob, Wbf + (size_t)3 * WELEMS,
                                                  bc, out);
}